// Round 24
// baseline (111.449 us; speedup 1.0000x reference)
//
#include <hip/hip_runtime.h>
#include <math.h>

#define NN 50000
#define NE 800000
#define BSH 7               // bucket = dst >> 7 (128 nodes/bucket)
#define NBUCK 391           // ceil(50000/128)
#define CAP 4096            // per-bucket capacity
#define CHUNK 4096          // edges per bscatter chunk
#define NCH ((NE + CHUNK - 1) / CHUNK)   // 196
#define K1B 782             // k1 blocks in merged kernel
#define EPT2 8              // edges per thread in merged bscatter (CHUNK/512)
#define SENT 50000          // sentinel node: Qh[SENT][*] = +inf (prescaled -> sig 0)
#define NL2E -1.4426950408889634f   // -log2(e)

typedef float4 f4;
typedef float2 f2;
typedef unsigned short u16;
typedef unsigned int u32;

__device__ __forceinline__ float sigf(float x) {          // plain sigmoid (k1's C)
    return __builtin_amdgcn_rcpf(1.0f + __expf(-x));
}

// prescaled sigmoid: y = -x*log2e already applied -> rcp(1 + 2^y)
__device__ __forceinline__ float sigf2(float y) {
    float e;
    asm("v_exp_f32 %0, %1" : "=v"(e) : "v"(y));
    return __builtin_amdgcn_rcpf(1.0f + e);
}

__device__ __forceinline__ u16 f32_to_bf16_rne(float f) {
    unsigned u = __float_as_uint(f);
    u += 0x7FFFu + ((u >> 16) & 1u);
    return (u16)(u >> 16);
}

__device__ __forceinline__ u32 pack_bf16(f2 v) {
    return ((u32)f32_to_bf16_rne(v.y) << 16) | (u32)f32_to_bf16_rne(v.x);
}

__device__ __forceinline__ float blo(u32 u) { return __uint_as_float(u << 16); }
__device__ __forceinline__ float bhi(u32 u) { return __uint_as_float(u & 0xFFFF0000u); }

// ---------------- Merged K1 + bscatter (R19-proven, f32 weights) ------------
// P' = -log2e*(z@W1^T+bn); Qh' = bf16(-log2e*(z@W2^T)) -- prescaled for sigf2.
// W1/W2 MUST stay f32 (R21 fail: P quant error amplified ~deg*sigma').
#define K1_WFLOATS (3 * 32 * 64 * 2)           // 12288 floats = 48KB
__global__ __launch_bounds__(512, 4) void k1_sc(
    const float* __restrict__ z,
    const float* __restrict__ Wc, const float* __restrict__ bc,
    const float* __restrict__ Wn, const float* __restrict__ bn,
    float* __restrict__ P, u16* __restrict__ Qh, float* __restrict__ C,
    const int* __restrict__ esrc, const int* __restrict__ edst,
    int* __restrict__ gcur, u32* __restrict__ ebuf)
{
    const int tid = threadIdx.x;
    if (blockIdx.x < K1B) {
        __shared__ float sh[K1_WFLOATS + 8 * 256];  // 48KB weights + 8KB tiles
        f2* w2 = (f2*)sh;
        for (int j = tid; j < 3 * 32 * 64; j += 512) {
            const int m = j >> 11, r = j & 2047;
            const int k2 = r >> 6, h = r & 63;
            const float* s = (m == 0) ? (Wc + h * 64 + 2 * k2)
                                      : (Wn + h * 128 + (m - 1) * 64 + 2 * k2);
            w2[(m * 32 + k2) * 64 + h] = *(const f2*)s;
        }
        __syncthreads();

        const int lane = tid & 63;
        const int wid  = tid >> 6;
        f4* tile = (f4*)(sh + K1_WFLOATS) + wid * 64;
        const f2* wl0 = w2;
        const f2* wl1 = w2 + 32 * 64;
        const f2* wl2 = w2 + 2 * 32 * 64;
        const float bcur = bc[lane], bnbr = bn[lane];

        const int gw = blockIdx.x * 8 + wid;
        const int nw = K1B * 8;
        for (int chunk = gw; chunk < NN / 4; chunk += nw) {
            const int n0 = chunk * 4;
            tile[lane] = *(const f4*)(z + n0 * 64 + lane * 4);
            float a0[4], a1[4], a2[4];
            #pragma unroll
            for (int ni = 0; ni < 4; ++ni) { a0[ni] = 0.f; a1[ni] = 0.f; a2[ni] = 0.f; }
            #pragma unroll 2
            for (int k4 = 0; k4 < 16; ++k4) {
                const f2 w0a = wl0[(2 * k4) * 64 + lane], w0b = wl0[(2 * k4 + 1) * 64 + lane];
                const f2 w1a = wl1[(2 * k4) * 64 + lane], w1b = wl1[(2 * k4 + 1) * 64 + lane];
                const f2 w2a = wl2[(2 * k4) * 64 + lane], w2b = wl2[(2 * k4 + 1) * 64 + lane];
                #pragma unroll
                for (int ni = 0; ni < 4; ++ni) {
                    const f4 zz = tile[ni * 16 + k4];  // uniform addr -> LDS broadcast
                    a0[ni] = fmaf(w0b.y, zz.w, fmaf(w0b.x, zz.z, fmaf(w0a.y, zz.y, fmaf(w0a.x, zz.x, a0[ni]))));
                    a1[ni] = fmaf(w1b.y, zz.w, fmaf(w1b.x, zz.z, fmaf(w1a.y, zz.y, fmaf(w1a.x, zz.x, a1[ni]))));
                    a2[ni] = fmaf(w2b.y, zz.w, fmaf(w2b.x, zz.z, fmaf(w2a.y, zz.y, fmaf(w2a.x, zz.x, a2[ni]))));
                }
            }
            #pragma unroll
            for (int ni = 0; ni < 4; ++ni) {
                const int n = n0 + ni;
                C[n * 64 + lane]  = sigf(a0[ni] + bcur);
                P[n * 64 + lane]  = (a1[ni] + bnbr) * NL2E;
                Qh[n * 64 + lane] = f32_to_bf16_rne(a2[ni] * NL2E);
            }
        }
    } else {
        // first scatter block also writes the sentinel Q row (+inf bf16)
        if (blockIdx.x == K1B && tid < 64) Qh[(size_t)SENT * 64 + tid] = 0x7F80u;

        __shared__ int cnt[NBUCK];
        __shared__ int gbase[NBUCK];
        __shared__ int lcur[NBUCK];
        for (int i = tid; i < NBUCK; i += 512) cnt[i] = 0;
        __syncthreads();

        const int base = (blockIdx.x - K1B) * CHUNK;
        u32 ent[EPT2];
        int nb[EPT2];
        #pragma unroll
        for (int t = 0; t < EPT2; ++t) {
            const int e = base + t * 512 + tid;
            if (e < NE) {
                const int d = edst[e], s = esrc[e];
                const int b = d >> BSH;
                ent[t] = ((u32)(d & 127) << 16) | (u32)s;
                nb[t] = b;
                atomicAdd(&cnt[b], 1);
            } else {
                nb[t] = -1;
            }
        }
        __syncthreads();
        for (int i = tid; i < NBUCK; i += 512) {
            gbase[i] = cnt[i] ? atomicAdd(&gcur[i], cnt[i]) : 0;
            lcur[i] = 0;
        }
        __syncthreads();
        #pragma unroll
        for (int t = 0; t < EPT2; ++t) {
            if (nb[t] >= 0) {
                const int li = atomicAdd(&lcur[nb[t]], 1);
                ebuf[nb[t] * CAP + gbase[nb[t]] + li] = ent[t];
            }
        }
    }
}

// One block per 128-node bucket. Node segments rounded to 8 entries (16B);
// pad slots = SENT. 48-entry sentinel guard past content.
__global__ __launch_bounds__(256) void k_bsort(const int* __restrict__ gcur,
                                               const u32* __restrict__ ebuf,
                                               u32* __restrict__ bd,
                                               u16* __restrict__ ss)
{
    __shared__ int hist[128];
    __shared__ int lcur[128];
    __shared__ int ps[128];
    __shared__ int tot;
    const int b = blockIdx.x;
    const int ecnt = gcur[b];
    const int e0 = b * CAP;
    const int n0 = b << BSH;
    const int t = threadIdx.x;

    if (t < 128) hist[t] = 0;
    __syncthreads();
    for (int j = t; j < ecnt; j += 256)
        atomicAdd(&hist[(ebuf[e0 + j] >> 16) & 127], 1);
    __syncthreads();
    if (t < 128) ps[t] = (hist[t] + 7) & ~7;     // rounded slot size
    __syncthreads();
    for (int o = 1; o < 128; o <<= 1) {
        int v = 0;
        if (t < 128 && t >= o) v = ps[t - o];
        __syncthreads();
        if (t < 128 && t >= o) ps[t] += v;
        __syncthreads();
    }
    if (t < 128) {
        const int a = hist[t];
        const int r = (a + 7) & ~7;
        const int excl = ps[t] - r;              // exclusive rounded offset
        lcur[t] = excl;
        const int n = n0 + t;
        if (n < NN) bd[n] = ((u32)(e0 + excl) << 8) | (u32)a;
        if (t == 127) tot = ps[127];
    }
    __syncthreads();
    const int zw = (tot + 48) >> 1;              // sentinel fill + guard
    u32* ssw = (u32*)(ss + e0);
    for (int j = t; j < zw; j += 256) ssw[j] = 0xC350C350u;  // SENT|SENT
    __syncthreads();
    for (int j = t; j < ecnt; j += 256) {
        const u32 ent = ebuf[e0 + j];
        const int p = atomicAdd(&lcur[(ent >> 16) & 127], 1);
        ss[e0 + p] = (u16)(ent & 0xFFFFu);
    }
}

// ---------------- K23 gather round: 4 edges per load -------------------------
// Lane l: group g = l>>4 handles edge 4j+g of each quad; loads dwordx2 (4 bf16,
// h = (l&15)*4..+3) of that edge's Q row. NL loads per round = 4*NL edges.
// Exact-size rounds (sentinel pads -> contribute exactly 0); all waits vmcnt(0).
template<int NL>    // NL in {2,4,6}: 8/16/24 edges, 2*NL index words
__device__ __forceinline__ void round_g4(const u16* __restrict__ ip,
                                         const u16* __restrict__ qbl4,
                                         int wofs, int sel, f4 p4,
                                         float (&acc)[4])
{
    uint4 iv0, iv1, iv2;
    asm volatile("global_load_dwordx4 %0, %1, off" : "=v"(iv0) : "v"(ip));
    if constexpr (NL >= 4)
        asm volatile("global_load_dwordx4 %0, %1, off offset:16" : "=v"(iv1) : "v"(ip));
    if constexpr (NL >= 6)
        asm volatile("global_load_dwordx4 %0, %1, off offset:32" : "=v"(iv2) : "v"(ip));
    asm volatile("s_waitcnt vmcnt(0)" ::: "memory");
    __builtin_amdgcn_sched_barrier(0);
    u32 wv[2 * NL];
    wv[0] = iv0.x; wv[1] = iv0.y; wv[2] = iv0.z; wv[3] = iv0.w;
    if constexpr (NL >= 4) { wv[4] = iv1.x; wv[5] = iv1.y; wv[6] = iv1.z; wv[7] = iv1.w; }
    if constexpr (NL >= 6) { wv[8] = iv2.x; wv[9] = iv2.y; wv[10] = iv2.z; wv[11] = iv2.w; }
    uint2 q[NL];
    #pragma unroll
    for (int j = 0; j < NL; ++j) {
        const u32 w = wv[2 * j + wofs];
        const u16* a = qbl4 + (((w >> sel) & 0xFFFFu) << 6);
        asm volatile("global_load_dwordx2 %0, %1, off" : "=v"(q[j]) : "v"(a));
    }
    asm volatile("s_waitcnt vmcnt(0)" ::: "memory");
    __builtin_amdgcn_sched_barrier(0);
    #pragma unroll
    for (int j = 0; j < NL; ++j) {
        acc[0] += sigf2(p4.x + blo(q[j].x));
        acc[1] += sigf2(p4.y + bhi(q[j].x));
        acc[2] += sigf2(p4.z + blo(q[j].y));
        acc[3] += sigf2(p4.w + bhi(q[j].y));
    }
}

// ---------------- Fused K2+K3: one wave per 4 dst nodes ---------------------
// Mixed-precision Wo in LDS (bf16 C-part 8KB + f32 NB-part 16KB) + 16KB
// tiles = 40KB -> 4 blocks/CU. Per node: exact-rdg 4-edge-per-load rounds,
// 2-level shfl_xor combine, then 4-node-amortized contraction.
__global__ __launch_bounds__(512, 8) void k23(
    const u32* __restrict__ bd, const u16* __restrict__ ss,
    const float* __restrict__ P, const u16* __restrict__ Qh,
    const float* __restrict__ C, const float* __restrict__ Wo,
    const float* __restrict__ bo, float* __restrict__ out)
{
    __shared__ u32 w1u[32 * 64];                // C-part Wo: bf16x2 (8KB)
    __shared__ f2  w2f[32 * 64];                // NB-part Wo: f32x2 (16KB)
    __shared__ float tiles[8 * 512];            // per-wave [4 nodes][C | NB]
    const int tid = threadIdx.x;
    for (int j = tid; j < 32 * 64; j += 512) {
        const int k2 = j >> 6, d = j & 63;
        w1u[k2 * 64 + d] = pack_bf16(*(const f2*)(Wo + d * 128 + 2 * k2));
        w2f[k2 * 64 + d] = *(const f2*)(Wo + d * 128 + 64 + 2 * k2);
    }
    __syncthreads();

    const int lane = tid & 63;
    const int wid  = tid >> 6;
    float* tile = tiles + wid * 512;
    const f4* t4 = (const f4*)tile;
    const int wofs = lane >> 5;                  // word offset within pair
    const int sel  = ((lane >> 4) & 1) * 16;     // lo/hi edge of the word
    const u16* qbl4 = Qh + (lane & 15) * 4;      // lane covers 4 bf16 of each row
    const float bout = bo[lane];

    for (int chunk = blockIdx.x * 8 + wid; chunk < NN / 4; chunk += gridDim.x * 8) {
        const int n0 = chunk * 4;
        #pragma unroll
        for (int i = 0; i < 4; ++i) {
            const int n = n0 + i;
            const u32 w = bd[n];
            const int beg = __builtin_amdgcn_readfirstlane((int)(w >> 8));
            const int dg  = __builtin_amdgcn_readfirstlane((int)(w & 255u));
            const int rdg = (dg + 7) & ~7;
            const f4 p4 = *(const f4*)(P + n * 64 + (lane & 15) * 4);
            tile[i * 128 + lane] = C[n * 64 + lane];
            float acc[4] = {0.f, 0.f, 0.f, 0.f};

            int jb = 0;
            for (; jb + 24 <= rdg; jb += 24)
                round_g4<6>(ss + beg + jb, qbl4, wofs, sel, p4, acc);
            const int rem = rdg - jb;            // 0, 8, or 16 (wave-uniform)
            if (rem == 16)     round_g4<4>(ss + beg + jb, qbl4, wofs, sel, p4, acc);
            else if (rem == 8) round_g4<2>(ss + beg + jb, qbl4, wofs, sel, p4, acc);

            // combine 4 lane-groups: lanes {l, l+16, l+32, l+48} share h range
            #pragma unroll
            for (int t = 0; t < 4; ++t) {
                acc[t] += __shfl_xor(acc[t], 16, 64);
                acc[t] += __shfl_xor(acc[t], 32, 64);
            }
            if (lane < 16) {
                f4 v; v.x = acc[0]; v.y = acc[1]; v.z = acc[2]; v.w = acc[3];
                *(f4*)(tile + i * 128 + 64 + lane * 4) = v;    // wave-internal
            }
        }

        // ---- contraction: out = tanh([C|NB] @ Wo^T + bo) ----
        float a2[4] = {0.f, 0.f, 0.f, 0.f};
        #pragma unroll 2
        for (int k4 = 0; k4 < 16; ++k4) {       // C-part (bf16 weights; |C|<=1)
            const u32 ua = w1u[(2 * k4) * 64 + lane];
            const u32 ub = w1u[(2 * k4 + 1) * 64 + lane];
            const float wa0 = blo(ua), wa1 = bhi(ua);
            const float wb0 = blo(ub), wb1 = bhi(ub);
            #pragma unroll
            for (int i = 0; i < 4; ++i) {
                const f4 hv = t4[i * 32 + k4];  // uniform addr -> LDS broadcast
                a2[i] = fmaf(wb1, hv.w, fmaf(wb0, hv.z, fmaf(wa1, hv.y, fmaf(wa0, hv.x, a2[i]))));
            }
        }
        #pragma unroll 2
        for (int k4 = 0; k4 < 16; ++k4) {       // NB-part (f32 weights)
            const f2 wa = w2f[(2 * k4) * 64 + lane];
            const f2 wb = w2f[(2 * k4 + 1) * 64 + lane];
            #pragma unroll
            for (int i = 0; i < 4; ++i) {
                const f4 hv = t4[i * 32 + 16 + k4];
                a2[i] = fmaf(wb.y, hv.w, fmaf(wb.x, hv.z, fmaf(wa.y, hv.y, fmaf(wa.x, hv.x, a2[i]))));
            }
        }
        #pragma unroll
        for (int i = 0; i < 4; ++i)
            out[(n0 + i) * 64 + lane] = tanhf(a2[i] + bout);
    }
}

extern "C" void kernel_launch(void* const* d_in, const int* in_sizes, int n_in,
                              void* d_out, int out_size, void* d_ws, size_t ws_size,
                              hipStream_t stream) {
    const float* z  = (const float*)d_in[0];
    const int* esrc = (const int*)d_in[1];
    const int* edst = (const int*)d_in[2];
    const float* Wc = (const float*)d_in[3];
    const float* bc = (const float*)d_in[4];
    const float* Wn = (const float*)d_in[5];
    const float* bn = (const float*)d_in[6];
    const float* Wo = (const float*)d_in[7];
    const float* bo = (const float*)d_in[8];
    float* out = (float*)d_out;

    float* P   = (float*)d_ws;                   // [NN*64] f32 (prescaled)
    float* C   = P + (size_t)NN * 64;            // [NN*64] f32
    u16* Qh    = (u16*)(C + (size_t)NN * 64);    // [(NN+1)*64] bf16 (prescaled + sentinel)
    u32* bd    = (u32*)(Qh + (size_t)(NN + 1) * 64); // [NN] packed (beg<<8)|deg
    int* gcur  = (int*)(bd + NN + 64);           // [512]
    u32* ebuf  = (u32*)(gcur + 512);             // [NBUCK*CAP] packed entries
    u16* ss    = (u16*)(ebuf + (size_t)NBUCK * CAP); // [NBUCK*CAP + pad] u16

    hipMemsetAsync(gcur, 0, 512 * sizeof(int), stream);
    k1_sc<<<K1B + NCH, 512, 0, stream>>>(z, Wc, bc, Wn, bn, P, Qh, C,
                                         esrc, edst, gcur, ebuf);
    k_bsort<<<NBUCK, 256, 0, stream>>>(gcur, ebuf, bd, ss);
    k23<<<1563, 512, 0, stream>>>(bd, ss, P, Qh, C, Wo, bo, out);
}

// Round 25
// 106.402 us; speedup vs baseline: 1.0474x; 1.0474x over previous
//
#include <hip/hip_runtime.h>
#include <math.h>

#define NN 50000
#define NE 800000
#define BSH 7               // bucket = dst >> 7 (128 nodes/bucket)
#define NBUCK 391           // ceil(50000/128)
#define CAP 4096            // per-bucket capacity
#define CHUNK 4096          // edges per bscatter chunk
#define NCH ((NE + CHUNK - 1) / CHUNK)   // 196
#define K1B 782             // k1 blocks in merged kernel
#define EPT2 8              // edges per thread in merged bscatter (CHUNK/512)
#define SENT 50000          // sentinel node: Qh[SENT][*] = +inf (prescaled -> sig 0)
#define NL2E -1.4426950408889634f   // -log2(e)

typedef float4 f4;
typedef float2 f2;
typedef unsigned short u16;
typedef unsigned int u32;

__device__ __forceinline__ float sigf(float x) {          // plain sigmoid (k1's C)
    return __builtin_amdgcn_rcpf(1.0f + __expf(-x));
}

// prescaled sigmoid: y = -x*log2e already applied -> rcp(1 + 2^y)
__device__ __forceinline__ float sigf2(float y) {
    float e;
    asm("v_exp_f32 %0, %1" : "=v"(e) : "v"(y));
    return __builtin_amdgcn_rcpf(1.0f + e);
}

__device__ __forceinline__ u16 f32_to_bf16_rne(float f) {
    unsigned u = __float_as_uint(f);
    u += 0x7FFFu + ((u >> 16) & 1u);
    return (u16)(u >> 16);
}

__device__ __forceinline__ u32 pack_bf16(f2 v) {
    return ((u32)f32_to_bf16_rne(v.y) << 16) | (u32)f32_to_bf16_rne(v.x);
}

__device__ __forceinline__ float blo(u32 u) { return __uint_as_float(u << 16); }
__device__ __forceinline__ float bhi(u32 u) { return __uint_as_float(u & 0xFFFF0000u); }

// ---------------- Merged K1 + bscatter (union'd LDS = 40KB, 4 blocks/CU) ----
// P' = -log2e*(z@W1^T+bn); Qh' = bf16(-log2e*(z@W2^T)) -- prescaled for sigf2.
// W1 f32 (P error enters ~deg edges coherently -- R21 fail proves bf16 unsafe).
// Wc bf16 (C error enters out once, ~3e-4). W2 bf16 (Q is bf16-rounded anyway).
__global__ __launch_bounds__(512, 8) void k1_sc(
    const float* __restrict__ z,
    const float* __restrict__ Wc, const float* __restrict__ bc,
    const float* __restrict__ Wn, const float* __restrict__ bn,
    float* __restrict__ P, u16* __restrict__ Qh, float* __restrict__ C,
    const int* __restrict__ esrc, const int* __restrict__ edst,
    int* __restrict__ gcur, u32* __restrict__ ebuf)
{
    __shared__ u32 shm[10240];                  // 40KB, union of both branches
    const int tid = threadIdx.x;
    if (blockIdx.x < K1B) {
        f2*  w1f   = (f2*)shm;                  // W1: [32*64] f32x2 (16KB)
        u32* wcU   = shm + 4096;                // Wc: [32*64] bf16x2 (8KB)
        u32* w2U   = shm + 6144;                // W2: [32*64] bf16x2 (8KB)
        f4*  ztile = (f4*)(shm + 8192);         // 8 waves x 64 f4 (8KB)
        for (int j = tid; j < 32 * 64; j += 512) {
            const int k2 = j >> 6, h = j & 63;
            w1f[j] = *(const f2*)(Wn + h * 128 + 2 * k2);
            wcU[j] = pack_bf16(*(const f2*)(Wc + h * 64 + 2 * k2));
            w2U[j] = pack_bf16(*(const f2*)(Wn + h * 128 + 64 + 2 * k2));
        }
        __syncthreads();

        const int lane = tid & 63;
        const int wid  = tid >> 6;
        f4* tile = ztile + wid * 64;
        const float bcur = bc[lane], bnbr = bn[lane];

        const int gw = blockIdx.x * 8 + wid;
        const int nw = K1B * 8;
        for (int chunk = gw; chunk < NN / 4; chunk += nw) {
            const int n0 = chunk * 4;
            tile[lane] = *(const f4*)(z + n0 * 64 + lane * 4);  // wave-private
            float a0[4], a1[4], a2[4];
            #pragma unroll
            for (int ni = 0; ni < 4; ++ni) { a0[ni] = 0.f; a1[ni] = 0.f; a2[ni] = 0.f; }
            #pragma unroll 2
            for (int k4 = 0; k4 < 16; ++k4) {
                const u32 uca = wcU[(2 * k4) * 64 + lane];
                const u32 ucb = wcU[(2 * k4 + 1) * 64 + lane];
                const f2  w1a = w1f[(2 * k4) * 64 + lane];
                const f2  w1b = w1f[(2 * k4 + 1) * 64 + lane];
                const u32 u2a = w2U[(2 * k4) * 64 + lane];
                const u32 u2b = w2U[(2 * k4 + 1) * 64 + lane];
                const float c0 = blo(uca), c1 = bhi(uca), c2 = blo(ucb), c3 = bhi(ucb);
                const float q0 = blo(u2a), q1 = bhi(u2a), q2 = blo(u2b), q3 = bhi(u2b);
                #pragma unroll
                for (int ni = 0; ni < 4; ++ni) {
                    const f4 zz = tile[ni * 16 + k4];  // uniform addr -> broadcast
                    a0[ni] = fmaf(c3, zz.w, fmaf(c2, zz.z, fmaf(c1, zz.y, fmaf(c0, zz.x, a0[ni]))));
                    a1[ni] = fmaf(w1b.y, zz.w, fmaf(w1b.x, zz.z, fmaf(w1a.y, zz.y, fmaf(w1a.x, zz.x, a1[ni]))));
                    a2[ni] = fmaf(q3, zz.w, fmaf(q2, zz.z, fmaf(q1, zz.y, fmaf(q0, zz.x, a2[ni]))));
                }
            }
            #pragma unroll
            for (int ni = 0; ni < 4; ++ni) {
                const int n = n0 + ni;
                C[n * 64 + lane]  = sigf(a0[ni] + bcur);
                P[n * 64 + lane]  = (a1[ni] + bnbr) * NL2E;
                Qh[n * 64 + lane] = f32_to_bf16_rne(a2[ni] * NL2E);
            }
        }
    } else {
        // first scatter block also writes the sentinel Q row (+inf bf16)
        if (blockIdx.x == K1B && tid < 64) Qh[(size_t)SENT * 64 + tid] = 0x7F80u;

        int* cnt   = (int*)shm;                 // [NBUCK]
        int* gbase = cnt + NBUCK;               // [NBUCK]
        int* lcur  = gbase + NBUCK;             // [NBUCK]
        for (int i = tid; i < NBUCK; i += 512) cnt[i] = 0;
        __syncthreads();

        const int base = (blockIdx.x - K1B) * CHUNK;
        u32 ent[EPT2];
        int nb[EPT2];
        #pragma unroll
        for (int t = 0; t < EPT2; ++t) {
            const int e = base + t * 512 + tid;
            if (e < NE) {
                const int d = edst[e], s = esrc[e];
                const int b = d >> BSH;
                ent[t] = ((u32)(d & 127) << 16) | (u32)s;
                nb[t] = b;
                atomicAdd(&cnt[b], 1);
            } else {
                nb[t] = -1;
            }
        }
        __syncthreads();
        for (int i = tid; i < NBUCK; i += 512) {
            gbase[i] = cnt[i] ? atomicAdd(&gcur[i], cnt[i]) : 0;
            lcur[i] = 0;
        }
        __syncthreads();
        #pragma unroll
        for (int t = 0; t < EPT2; ++t) {
            if (nb[t] >= 0) {
                const int li = atomicAdd(&lcur[nb[t]], 1);
                ebuf[nb[t] * CAP + gbase[nb[t]] + li] = ent[t];
            }
        }
    }
}

// One block per 128-node bucket. Node segments rounded to 8 entries (16B);
// pad slots = SENT. 48-entry sentinel guard past content.
__global__ __launch_bounds__(256) void k_bsort(const int* __restrict__ gcur,
                                               const u32* __restrict__ ebuf,
                                               u32* __restrict__ bd,
                                               u16* __restrict__ ss)
{
    __shared__ int hist[128];
    __shared__ int lcur[128];
    __shared__ int ps[128];
    __shared__ int tot;
    const int b = blockIdx.x;
    const int ecnt = gcur[b];
    const int e0 = b * CAP;
    const int n0 = b << BSH;
    const int t = threadIdx.x;

    if (t < 128) hist[t] = 0;
    __syncthreads();
    for (int j = t; j < ecnt; j += 256)
        atomicAdd(&hist[(ebuf[e0 + j] >> 16) & 127], 1);
    __syncthreads();
    if (t < 128) ps[t] = (hist[t] + 7) & ~7;     // rounded slot size
    __syncthreads();
    for (int o = 1; o < 128; o <<= 1) {
        int v = 0;
        if (t < 128 && t >= o) v = ps[t - o];
        __syncthreads();
        if (t < 128 && t >= o) ps[t] += v;
        __syncthreads();
    }
    if (t < 128) {
        const int a = hist[t];
        const int r = (a + 7) & ~7;
        const int excl = ps[t] - r;              // exclusive rounded offset
        lcur[t] = excl;
        const int n = n0 + t;
        if (n < NN) bd[n] = ((u32)(e0 + excl) << 8) | (u32)a;
        if (t == 127) tot = ps[127];
    }
    __syncthreads();
    const int zw = (tot + 48) >> 1;              // sentinel fill + guard
    u32* ssw = (u32*)(ss + e0);
    for (int j = t; j < zw; j += 256) ssw[j] = 0xC350C350u;  // SENT|SENT
    __syncthreads();
    for (int j = t; j < ecnt; j += 256) {
        const u32 ent = ebuf[e0 + j];
        const int p = atomicAdd(&lcur[(ent >> 16) & 127], 1);
        ss[e0 + p] = (u16)(ent & 0xFFFFu);
    }
}

// One gather round, 2 edges per slot word. NW slot words in {4,8,12} =
// {8,16,24} edges. Lanes 0-31 gather the even edge's row (4B/lane), lanes
// 32-63 the odd edge's. One idx-wait + one gather-wait per round. Exact
// size via sentinel pads (contribute exactly 0); all waits vmcnt(0).
template<int NW>
__device__ __forceinline__ void round_g2(const u16* __restrict__ ip,
                                         const u16* __restrict__ qbl2,
                                         int sel, f2 p2,
                                         float& acc0, float& acc1)
{
    uint4 iv0, iv1, iv2;
    asm volatile("global_load_dwordx4 %0, %1, off" : "=v"(iv0) : "v"(ip));
    if constexpr (NW >= 8)
        asm volatile("global_load_dwordx4 %0, %1, off offset:16" : "=v"(iv1) : "v"(ip));
    if constexpr (NW >= 12)
        asm volatile("global_load_dwordx4 %0, %1, off offset:32" : "=v"(iv2) : "v"(ip));
    asm volatile("s_waitcnt vmcnt(0)" ::: "memory");
    __builtin_amdgcn_sched_barrier(0);
    u32 wv[NW];
    wv[0] = iv0.x; wv[1] = iv0.y; wv[2] = iv0.z; wv[3] = iv0.w;
    if constexpr (NW >= 8)  { wv[4] = iv1.x; wv[5] = iv1.y; wv[6] = iv1.z; wv[7] = iv1.w; }
    if constexpr (NW >= 12) { wv[8] = iv2.x; wv[9] = iv2.y; wv[10] = iv2.z; wv[11] = iv2.w; }
    u32 q[NW];
    #pragma unroll
    for (int w = 0; w < NW; ++w) {
        const u16* a = qbl2 + (((wv[w] >> sel) & 0xFFFFu) << 6);
        asm volatile("global_load_dword %0, %1, off" : "=v"(q[w]) : "v"(a));
    }
    asm volatile("s_waitcnt vmcnt(0)" ::: "memory");
    __builtin_amdgcn_sched_barrier(0);
    #pragma unroll
    for (int w = 0; w < NW; ++w) {
        acc0 += sigf2(p2.x + blo(q[w]));
        acc1 += sigf2(p2.y + bhi(q[w]));
    }
}

// ---------------- Fused K2+K3: one wave per 4 dst nodes (R19-proven) --------
// Mixed-precision Wo in LDS (bf16 C-part 8KB + f32 NB-part 16KB) + 16KB
// tiles = 40KB -> 4 blocks/CU. Per node: exact-rdg 2-edge-slot rounds,
// shfl_xor(32) half-wave combine, then 4-node-amortized contraction.
__global__ __launch_bounds__(512, 8) void k23(
    const u32* __restrict__ bd, const u16* __restrict__ ss,
    const float* __restrict__ P, const u16* __restrict__ Qh,
    const float* __restrict__ C, const float* __restrict__ Wo,
    const float* __restrict__ bo, float* __restrict__ out)
{
    __shared__ u32 w1u[32 * 64];                // C-part Wo: bf16x2 (8KB)
    __shared__ f2  w2f[32 * 64];                // NB-part Wo: f32x2 (16KB)
    __shared__ float tiles[8 * 512];            // per-wave [4 nodes][C | NB]
    const int tid = threadIdx.x;
    for (int j = tid; j < 32 * 64; j += 512) {
        const int k2 = j >> 6, d = j & 63;
        w1u[k2 * 64 + d] = pack_bf16(*(const f2*)(Wo + d * 128 + 2 * k2));
        w2f[k2 * 64 + d] = *(const f2*)(Wo + d * 128 + 64 + 2 * k2);
    }
    __syncthreads();

    const int lane = tid & 63;
    const int wid  = tid >> 6;
    float* tile = tiles + wid * 512;
    const f4* t4 = (const f4*)tile;
    const int sel = (lane >= 32) ? 16 : 0;
    const u16* qbl2 = Qh + (lane & 31) * 2;     // lane covers 2 bf16 of each row
    const float bout = bo[lane];

    for (int chunk = blockIdx.x * 8 + wid; chunk < NN / 4; chunk += gridDim.x * 8) {
        const int n0 = chunk * 4;
        #pragma unroll
        for (int i = 0; i < 4; ++i) {
            const int n = n0 + i;
            const u32 w = bd[n];
            const int beg = __builtin_amdgcn_readfirstlane((int)(w >> 8));
            const int dg  = __builtin_amdgcn_readfirstlane((int)(w & 255u));
            const int rdg = (dg + 7) & ~7;
            const f2 p2 = *(const f2*)(P + n * 64 + 2 * (lane & 31));
            tile[i * 128 + lane] = C[n * 64 + lane];
            float acc0 = 0.f, acc1 = 0.f;

            int jb = 0;
            for (; jb + 24 <= rdg; jb += 24)
                round_g2<12>(ss + beg + jb, qbl2, sel, p2, acc0, acc1);
            const int rem = rdg - jb;            // 0, 8, or 16 (wave-uniform)
            if (rem == 16)     round_g2<8>(ss + beg + jb, qbl2, sel, p2, acc0, acc1);
            else if (rem == 8) round_g2<4>(ss + beg + jb, qbl2, sel, p2, acc0, acc1);

            // combine half-waves: lanes l and l+32 hold the same h pair
            const float s0 = __shfl_xor(acc0, 32, 64);
            const float s1 = __shfl_xor(acc1, 32, 64);
            if (lane < 32) {
                f2 v; v.x = acc0 + s0; v.y = acc1 + s1;
                *(f2*)(tile + i * 128 + 64 + 2 * lane) = v;   // wave-internal
            }
        }

        // ---- contraction: out = tanh([C|NB] @ Wo^T + bo) ----
        float a2[4] = {0.f, 0.f, 0.f, 0.f};
        #pragma unroll 2
        for (int k4 = 0; k4 < 16; ++k4) {       // C-part (bf16 weights; |C|<=1)
            const u32 ua = w1u[(2 * k4) * 64 + lane];
            const u32 ub = w1u[(2 * k4 + 1) * 64 + lane];
            const float wa0 = blo(ua), wa1 = bhi(ua);
            const float wb0 = blo(ub), wb1 = bhi(ub);
            #pragma unroll
            for (int i = 0; i < 4; ++i) {
                const f4 hv = t4[i * 32 + k4];  // uniform addr -> LDS broadcast
                a2[i] = fmaf(wb1, hv.w, fmaf(wb0, hv.z, fmaf(wa1, hv.y, fmaf(wa0, hv.x, a2[i]))));
            }
        }
        #pragma unroll 2
        for (int k4 = 0; k4 < 16; ++k4) {       // NB-part (f32 weights)
            const f2 wa = w2f[(2 * k4) * 64 + lane];
            const f2 wb = w2f[(2 * k4 + 1) * 64 + lane];
            #pragma unroll
            for (int i = 0; i < 4; ++i) {
                const f4 hv = t4[i * 32 + 16 + k4];
                a2[i] = fmaf(wb.y, hv.w, fmaf(wb.x, hv.z, fmaf(wa.y, hv.y, fmaf(wa.x, hv.x, a2[i]))));
            }
        }
        #pragma unroll
        for (int i = 0; i < 4; ++i)
            out[(n0 + i) * 64 + lane] = tanhf(a2[i] + bout);
    }
}

extern "C" void kernel_launch(void* const* d_in, const int* in_sizes, int n_in,
                              void* d_out, int out_size, void* d_ws, size_t ws_size,
                              hipStream_t stream) {
    const float* z  = (const float*)d_in[0];
    const int* esrc = (const int*)d_in[1];
    const int* edst = (const int*)d_in[2];
    const float* Wc = (const float*)d_in[3];
    const float* bc = (const float*)d_in[4];
    const float* Wn = (const float*)d_in[5];
    const float* bn = (const float*)d_in[6];
    const float* Wo = (const float*)d_in[7];
    const float* bo = (const float*)d_in[8];
    float* out = (float*)d_out;

    float* P   = (float*)d_ws;                   // [NN*64] f32 (prescaled)
    float* C   = P + (size_t)NN * 64;            // [NN*64] f32
    u16* Qh    = (u16*)(C + (size_t)NN * 64);    // [(NN+1)*64] bf16 (prescaled + sentinel)
    u32* bd    = (u32*)(Qh + (size_t)(NN + 1) * 64); // [NN] packed (beg<<8)|deg
    int* gcur  = (int*)(bd + NN + 64);           // [512]
    u32* ebuf  = (u32*)(gcur + 512);             // [NBUCK*CAP] packed entries
    u16* ss    = (u16*)(ebuf + (size_t)NBUCK * CAP); // [NBUCK*CAP + pad] u16

    hipMemsetAsync(gcur, 0, 512 * sizeof(int), stream);
    k1_sc<<<K1B + NCH, 512, 0, stream>>>(z, Wc, bc, Wn, bn, P, Qh, C,
                                         esrc, edst, gcur, ebuf);
    k_bsort<<<NBUCK, 256, 0, stream>>>(gcur, ebuf, bd, ss);
    k23<<<1563, 512, 0, stream>>>(bd, ss, P, Qh, C, Wo, bo, out);
}

// Round 26
// 102.622 us; speedup vs baseline: 1.0860x; 1.0368x over previous
//
#include <hip/hip_runtime.h>
#include <math.h>

#define NN 50000
#define NE 800000
#define BSH 7               // bucket = dst >> 7 (128 nodes/bucket)
#define NBUCK 391           // ceil(50000/128)
#define CAP 4096            // per-bucket capacity
#define CHUNK 4096          // edges per bscatter chunk
#define NCH ((NE + CHUNK - 1) / CHUNK)   // 196
#define K1B 782             // k1 blocks in merged kernel
#define EPT2 8              // edges per thread in merged bscatter (CHUNK/512)
#define SENT 50000          // sentinel node: Qh[SENT][*] = +inf (prescaled -> sig 0)
#define NL2E -1.4426950408889634f   // -log2(e)

typedef float4 f4;
typedef float2 f2;
typedef unsigned short u16;
typedef unsigned int u32;

__device__ __forceinline__ float sigf(float x) {          // plain sigmoid (k1's C)
    return __builtin_amdgcn_rcpf(1.0f + __expf(-x));
}

// prescaled sigmoid: y = -x*log2e already applied -> rcp(1 + 2^y)
__device__ __forceinline__ float sigf2(float y) {
    float e;
    asm("v_exp_f32 %0, %1" : "=v"(e) : "v"(y));
    return __builtin_amdgcn_rcpf(1.0f + e);
}

__device__ __forceinline__ u16 f32_to_bf16_rne(float f) {
    unsigned u = __float_as_uint(f);
    u += 0x7FFFu + ((u >> 16) & 1u);
    return (u16)(u >> 16);
}

__device__ __forceinline__ u32 pack_bf16(f2 v) {
    return ((u32)f32_to_bf16_rne(v.y) << 16) | (u32)f32_to_bf16_rne(v.x);
}

__device__ __forceinline__ float blo(u32 u) { return __uint_as_float(u << 16); }
__device__ __forceinline__ float bhi(u32 u) { return __uint_as_float(u & 0xFFFF0000u); }

// ---------------- Merged K1 + bscatter (independent work, one launch) -------
// P' = -log2e*(z@W1^T+bn); Qh' = bf16(-log2e*(z@W2^T)) -- prescaled for sigf2.
// W1/W2 stay f32: P quantization error is amplified ~deg*sigma' (R21 fail);
// bf16 Wc/W2 in k1 cost more unpack-VALU than the occupancy buys (R25).
#define K1_WFLOATS (3 * 32 * 64 * 2)           // 12288 floats = 48KB
__global__ __launch_bounds__(512, 4) void k1_sc(
    const float* __restrict__ z,
    const float* __restrict__ Wc, const float* __restrict__ bc,
    const float* __restrict__ Wn, const float* __restrict__ bn,
    float* __restrict__ P, u16* __restrict__ Qh, float* __restrict__ C,
    const int* __restrict__ esrc, const int* __restrict__ edst,
    int* __restrict__ gcur, u32* __restrict__ ebuf)
{
    const int tid = threadIdx.x;
    if (blockIdx.x < K1B) {
        __shared__ float sh[K1_WFLOATS + 8 * 256];  // 48KB weights + 8KB tiles
        f2* w2 = (f2*)sh;
        for (int j = tid; j < 3 * 32 * 64; j += 512) {
            const int m = j >> 11, r = j & 2047;
            const int k2 = r >> 6, h = r & 63;
            const float* s = (m == 0) ? (Wc + h * 64 + 2 * k2)
                                      : (Wn + h * 128 + (m - 1) * 64 + 2 * k2);
            w2[(m * 32 + k2) * 64 + h] = *(const f2*)s;
        }
        __syncthreads();

        const int lane = tid & 63;
        const int wid  = tid >> 6;
        f4* tile = (f4*)(sh + K1_WFLOATS) + wid * 64;
        const f2* wl0 = w2;
        const f2* wl1 = w2 + 32 * 64;
        const f2* wl2 = w2 + 2 * 32 * 64;
        const float bcur = bc[lane], bnbr = bn[lane];

        const int gw = blockIdx.x * 8 + wid;
        const int nw = K1B * 8;
        for (int chunk = gw; chunk < NN / 4; chunk += nw) {
            const int n0 = chunk * 4;
            tile[lane] = *(const f4*)(z + n0 * 64 + lane * 4);
            float a0[4], a1[4], a2[4];
            #pragma unroll
            for (int ni = 0; ni < 4; ++ni) { a0[ni] = 0.f; a1[ni] = 0.f; a2[ni] = 0.f; }
            #pragma unroll 2
            for (int k4 = 0; k4 < 16; ++k4) {
                const f2 w0a = wl0[(2 * k4) * 64 + lane], w0b = wl0[(2 * k4 + 1) * 64 + lane];
                const f2 w1a = wl1[(2 * k4) * 64 + lane], w1b = wl1[(2 * k4 + 1) * 64 + lane];
                const f2 w2a = wl2[(2 * k4) * 64 + lane], w2b = wl2[(2 * k4 + 1) * 64 + lane];
                #pragma unroll
                for (int ni = 0; ni < 4; ++ni) {
                    const f4 zz = tile[ni * 16 + k4];  // uniform addr -> LDS broadcast
                    a0[ni] = fmaf(w0b.y, zz.w, fmaf(w0b.x, zz.z, fmaf(w0a.y, zz.y, fmaf(w0a.x, zz.x, a0[ni]))));
                    a1[ni] = fmaf(w1b.y, zz.w, fmaf(w1b.x, zz.z, fmaf(w1a.y, zz.y, fmaf(w1a.x, zz.x, a1[ni]))));
                    a2[ni] = fmaf(w2b.y, zz.w, fmaf(w2b.x, zz.z, fmaf(w2a.y, zz.y, fmaf(w2a.x, zz.x, a2[ni]))));
                }
            }
            #pragma unroll
            for (int ni = 0; ni < 4; ++ni) {
                const int n = n0 + ni;
                C[n * 64 + lane]  = sigf(a0[ni] + bcur);
                P[n * 64 + lane]  = (a1[ni] + bnbr) * NL2E;
                Qh[n * 64 + lane] = f32_to_bf16_rne(a2[ni] * NL2E);
            }
        }
    } else {
        // first scatter block also writes the sentinel Q row (+inf bf16)
        if (blockIdx.x == K1B && tid < 64) Qh[(size_t)SENT * 64 + tid] = 0x7F80u;

        __shared__ int cnt[NBUCK];
        __shared__ int gbase[NBUCK];
        __shared__ int lcur[NBUCK];
        for (int i = tid; i < NBUCK; i += 512) cnt[i] = 0;
        __syncthreads();

        const int base = (blockIdx.x - K1B) * CHUNK;
        u32 ent[EPT2];
        int nb[EPT2];
        #pragma unroll
        for (int t = 0; t < EPT2; ++t) {
            const int e = base + t * 512 + tid;
            if (e < NE) {
                const int d = edst[e], s = esrc[e];
                const int b = d >> BSH;
                ent[t] = ((u32)(d & 127) << 16) | (u32)s;
                nb[t] = b;
                atomicAdd(&cnt[b], 1);
            } else {
                nb[t] = -1;
            }
        }
        __syncthreads();
        for (int i = tid; i < NBUCK; i += 512) {
            gbase[i] = cnt[i] ? atomicAdd(&gcur[i], cnt[i]) : 0;
            lcur[i] = 0;
        }
        __syncthreads();
        #pragma unroll
        for (int t = 0; t < EPT2; ++t) {
            if (nb[t] >= 0) {
                const int li = atomicAdd(&lcur[nb[t]], 1);
                ebuf[nb[t] * CAP + gbase[nb[t]] + li] = ent[t];
            }
        }
    }
}

// One block per 128-node bucket. Node segments rounded to 8 entries (16B);
// pad slots = SENT (gather hits +inf row -> contributes exactly 0).
__global__ __launch_bounds__(256) void k_bsort(const int* __restrict__ gcur,
                                               const u32* __restrict__ ebuf,
                                               u32* __restrict__ bd,
                                               u16* __restrict__ ss)
{
    __shared__ int hist[128];
    __shared__ int lcur[128];
    __shared__ int ps[128];
    __shared__ int tot;
    const int b = blockIdx.x;
    const int ecnt = gcur[b];
    const int e0 = b * CAP;
    const int n0 = b << BSH;
    const int t = threadIdx.x;

    if (t < 128) hist[t] = 0;
    __syncthreads();
    for (int j = t; j < ecnt; j += 256)
        atomicAdd(&hist[(ebuf[e0 + j] >> 16) & 127], 1);
    __syncthreads();
    if (t < 128) ps[t] = (hist[t] + 7) & ~7;     // rounded slot size
    __syncthreads();
    for (int o = 1; o < 128; o <<= 1) {
        int v = 0;
        if (t < 128 && t >= o) v = ps[t - o];
        __syncthreads();
        if (t < 128 && t >= o) ps[t] += v;
        __syncthreads();
    }
    if (t < 128) {
        const int a = hist[t];
        const int r = (a + 7) & ~7;
        const int excl = ps[t] - r;              // exclusive rounded offset
        lcur[t] = excl;
        const int n = n0 + t;
        if (n < NN) bd[n] = ((u32)(e0 + excl) << 8) | (u32)a;
        if (t == 127) tot = ps[127];
    }
    __syncthreads();
    const int zw = (tot + 48) >> 1;              // sentinel fill + guard
    u32* ssw = (u32*)(ss + e0);
    for (int j = t; j < zw; j += 256) ssw[j] = 0xC350C350u;  // SENT|SENT
    __syncthreads();
    for (int j = t; j < ecnt; j += 256) {
        const u32 ent = ebuf[e0 + j];
        const int p = atomicAdd(&lcur[(ent >> 16) & 127], 1);
        ss[e0 + p] = (u16)(ent & 0xFFFFu);
    }
}

// One gather round, 2 edges per slot word. NW slot words in {4,8,12} =
// {8,16,24} edges. Lanes 0-31 gather the even edge's row (4B/lane), lanes
// 32-63 the odd edge's. One idx-wait + one gather-wait per round.
template<int NW>
__device__ __forceinline__ void round_g2(const u16* __restrict__ ip,
                                         const u16* __restrict__ qbl2,
                                         int sel, f2 p2,
                                         float& acc0, float& acc1)
{
    uint4 iv0, iv1, iv2;
    asm volatile("global_load_dwordx4 %0, %1, off" : "=v"(iv0) : "v"(ip));
    if constexpr (NW >= 8)
        asm volatile("global_load_dwordx4 %0, %1, off offset:16" : "=v"(iv1) : "v"(ip));
    if constexpr (NW >= 12)
        asm volatile("global_load_dwordx4 %0, %1, off offset:32" : "=v"(iv2) : "v"(ip));
    asm volatile("s_waitcnt vmcnt(0)" ::: "memory");
    __builtin_amdgcn_sched_barrier(0);
    u32 wv[NW];
    wv[0] = iv0.x; wv[1] = iv0.y; wv[2] = iv0.z; wv[3] = iv0.w;
    if constexpr (NW >= 8)  { wv[4] = iv1.x; wv[5] = iv1.y; wv[6] = iv1.z; wv[7] = iv1.w; }
    if constexpr (NW >= 12) { wv[8] = iv2.x; wv[9] = iv2.y; wv[10] = iv2.z; wv[11] = iv2.w; }
    u32 q[NW];
    #pragma unroll
    for (int w = 0; w < NW; ++w) {
        const u32 sv = (wv[w] >> sel) & 0xFFFFu;       // lane<32: even edge; else odd
        const u16* a = qbl2 + (sv << 6);
        asm volatile("global_load_dword %0, %1, off" : "=v"(q[w]) : "v"(a));
    }
    asm volatile("s_waitcnt vmcnt(0)" ::: "memory");
    __builtin_amdgcn_sched_barrier(0);
    #pragma unroll
    for (int w = 0; w < NW; ++w) {
        acc0 += sigf2(p2.x + blo(q[w]));
        acc1 += sigf2(p2.y + bhi(q[w]));
    }
}

// ---------------- Fused K2+K3: one wave per 4 dst nodes ---------------------
// Mixed-precision Wo in LDS (bf16 C-part 8KB + f32 NB-part 16KB) + 16KB
// tiles = 40KB -> 4 blocks/CU. Per node: exact-rdg 2-edge-slot rounds,
// shfl_xor(32) half-wave combine, then 4-node-amortized contraction.
__global__ __launch_bounds__(512, 8) void k23(
    const u32* __restrict__ bd, const u16* __restrict__ ss,
    const float* __restrict__ P, const u16* __restrict__ Qh,
    const float* __restrict__ C, const float* __restrict__ Wo,
    const float* __restrict__ bo, float* __restrict__ out)
{
    __shared__ u32 w1u[32 * 64];                // C-part Wo: bf16x2 (8KB)
    __shared__ f2  w2f[32 * 64];                // NB-part Wo: f32x2 (16KB)
    __shared__ float tiles[8 * 512];            // per-wave [4 nodes][C | NB]
    const int tid = threadIdx.x;
    for (int j = tid; j < 32 * 64; j += 512) {
        const int k2 = j >> 6, d = j & 63;
        w1u[k2 * 64 + d] = pack_bf16(*(const f2*)(Wo + d * 128 + 2 * k2));
        w2f[k2 * 64 + d] = *(const f2*)(Wo + d * 128 + 64 + 2 * k2);
    }
    __syncthreads();

    const int lane = tid & 63;
    const int wid  = tid >> 6;
    float* tile = tiles + wid * 512;
    const f4* t4 = (const f4*)tile;
    const int sel = (lane >= 32) ? 16 : 0;
    const u16* qbl2 = Qh + (lane & 31) * 2;     // lane covers 2 bf16 of each row
    const float bout = bo[lane];

    for (int chunk = blockIdx.x * 8 + wid; chunk < NN / 4; chunk += gridDim.x * 8) {
        const int n0 = chunk * 4;
        #pragma unroll
        for (int i = 0; i < 4; ++i) {
            const int n = n0 + i;
            const u32 w = bd[n];
            const int beg = __builtin_amdgcn_readfirstlane((int)(w >> 8));
            const int dg  = __builtin_amdgcn_readfirstlane((int)(w & 255u));
            const int rdg = (dg + 7) & ~7;
            const f2 p2 = *(const f2*)(P + n * 64 + 2 * (lane & 31));
            tile[i * 128 + lane] = C[n * 64 + lane];
            float acc0 = 0.f, acc1 = 0.f;

            int jb = 0;
            for (; jb + 24 <= rdg; jb += 24)
                round_g2<12>(ss + beg + jb, qbl2, sel, p2, acc0, acc1);
            const int rem = rdg - jb;            // 0, 8, or 16 (wave-uniform)
            if (rem == 16)     round_g2<8>(ss + beg + jb, qbl2, sel, p2, acc0, acc1);
            else if (rem == 8) round_g2<4>(ss + beg + jb, qbl2, sel, p2, acc0, acc1);

            // combine half-waves: lanes l and l+32 hold the same h pair
            const float s0 = __shfl_xor(acc0, 32, 64);
            const float s1 = __shfl_xor(acc1, 32, 64);
            if (lane < 32) {
                f2 v; v.x = acc0 + s0; v.y = acc1 + s1;
                *(f2*)(tile + i * 128 + 64 + 2 * lane) = v;   // wave-internal
            }
        }

        // ---- contraction: out = tanh([C|NB] @ Wo^T + bo) ----
        float a2[4] = {0.f, 0.f, 0.f, 0.f};
        #pragma unroll 2
        for (int k4 = 0; k4 < 16; ++k4) {       // C-part (bf16 weights; |C|<=1)
            const u32 ua = w1u[(2 * k4) * 64 + lane];
            const u32 ub = w1u[(2 * k4 + 1) * 64 + lane];
            const float wa0 = blo(ua), wa1 = bhi(ua);
            const float wb0 = blo(ub), wb1 = bhi(ub);
            #pragma unroll
            for (int i = 0; i < 4; ++i) {
                const f4 hv = t4[i * 32 + k4];   // uniform addr -> LDS broadcast
                a2[i] = fmaf(wb1, hv.w, fmaf(wb0, hv.z, fmaf(wa1, hv.y, fmaf(wa0, hv.x, a2[i]))));
            }
        }
        #pragma unroll 2
        for (int k4 = 0; k4 < 16; ++k4) {       // NB-part (f32 weights)
            const f2 wa = w2f[(2 * k4) * 64 + lane];
            const f2 wb = w2f[(2 * k4 + 1) * 64 + lane];
            #pragma unroll
            for (int i = 0; i < 4; ++i) {
                const f4 hv = t4[i * 32 + 16 + k4];
                a2[i] = fmaf(wb.y, hv.w, fmaf(wb.x, hv.z, fmaf(wa.y, hv.y, fmaf(wa.x, hv.x, a2[i]))));
            }
        }
        #pragma unroll
        for (int i = 0; i < 4; ++i)
            out[(n0 + i) * 64 + lane] = tanhf(a2[i] + bout);
    }
}

extern "C" void kernel_launch(void* const* d_in, const int* in_sizes, int n_in,
                              void* d_out, int out_size, void* d_ws, size_t ws_size,
                              hipStream_t stream) {
    const float* z  = (const float*)d_in[0];
    const int* esrc = (const int*)d_in[1];
    const int* edst = (const int*)d_in[2];
    const float* Wc = (const float*)d_in[3];
    const float* bc = (const float*)d_in[4];
    const float* Wn = (const float*)d_in[5];
    const float* bn = (const float*)d_in[6];
    const float* Wo = (const float*)d_in[7];
    const float* bo = (const float*)d_in[8];
    float* out = (float*)d_out;

    float* P   = (float*)d_ws;                   // [NN*64] f32 (prescaled)
    float* C   = P + (size_t)NN * 64;            // [NN*64] f32
    u16* Qh    = (u16*)(C + (size_t)NN * 64);    // [(NN+1)*64] bf16 (prescaled + sentinel)
    u32* bd    = (u32*)(Qh + (size_t)(NN + 1) * 64); // [NN] packed (beg<<8)|deg
    int* gcur  = (int*)(bd + NN + 64);           // [512]
    u32* ebuf  = (u32*)(gcur + 512);             // [NBUCK*CAP] packed entries
    u16* ss    = (u16*)(ebuf + (size_t)NBUCK * CAP); // [NBUCK*CAP + pad] u16

    hipMemsetAsync(gcur, 0, 512 * sizeof(int), stream);
    k1_sc<<<K1B + NCH, 512, 0, stream>>>(z, Wc, bc, Wn, bn, P, Qh, C,
                                         esrc, edst, gcur, ebuf);
    k_bsort<<<NBUCK, 256, 0, stream>>>(gcur, ebuf, bd, ss);
    k23<<<1563, 512, 0, stream>>>(bd, ss, P, Qh, C, Wo, bo, out);
}